// Round 2
// baseline (187.687 us; speedup 1.0000x reference)
//
#include <hip/hip_runtime.h>

// Attention_77730318123148 — B=2,S=2048,D=1024,H=16,HD=64. fp32 I/O, bf16 MFMA compute.
// R13: attn LDS-traffic cut — 2-wave blocks (128 thr), each wave owns 32 q-rows (2 q-frags),
// so every K/V ds_read_b128 feeds 2 MFMAs (FLOP/LDS-byte 14.2 -> 25.6). Same 64-row q-tile,
// same 1024-block quarter-balanced grid (66 units/CU), LDS 40960B -> 4 blocks/CU.
// gemm_qkv (R10) / gemm_out / prep unchanged.

#define DD 1024
#define SS 2048
#define BB 2
#define HH 16
#define HD 64
#define QSCALE 0.18033688011112042f   // 0.125 * log2(e)

typedef __attribute__((ext_vector_type(8))) short short8;   // 8 bf16 (A/B frag)
typedef __attribute__((ext_vector_type(4))) float float4v;  // C/D frag
typedef unsigned short ushort;
typedef unsigned int uint;

__device__ inline ushort f2bf(float f) {       // RNE (input conversion fidelity)
    union { float f; uint i; } v; v.f = f;
    uint r = v.i + 0x7FFF + ((v.i >> 16) & 1);
    return (ushort)(r >> 16);
}
#if __has_builtin(__builtin_amdgcn_cvt_pk_bf16_f32)
typedef __bf16 bf16x2 __attribute__((ext_vector_type(2)));
__device__ inline uint pack_bf2(float a, float b) {   // 1 inst, RNE
    union { bf16x2 v; uint u; } c;
    c.v = __builtin_amdgcn_cvt_pk_bf16_f32(a, b);
    return c.u;
}
#else
__device__ inline uint pack_bf2(float a, float b) {   // fallback: round-half-up
    union { float f; uint i; } x, y; x.f = a; y.f = b;
    return ((x.i + 0x8000u) >> 16) | (((y.i + 0x8000u) >> 16) << 16);
}
#endif

__device__ __forceinline__ void cp16(const ushort* g, ushort* l) {
    __builtin_amdgcn_global_load_lds((const __attribute__((address_space(1))) void*)g,
                                     (__attribute__((address_space(3))) void*)l,
                                     16, 0, 0);
}

// ---------------- prep: cvt x (4096 blk) | cvt Wo (1024 blk) | transpose W3 (768 blk) ----
__global__ __launch_bounds__(256) void prep(const float* __restrict__ x,
                                            const float* __restrict__ Wo,
                                            const float* __restrict__ Wq,
                                            const float* __restrict__ Wk,
                                            const float* __restrict__ Wv,
                                            ushort* __restrict__ xb,
                                            ushort* __restrict__ Wob,
                                            ushort* __restrict__ W3T) {
    __shared__ ushort T[64][65];
    int bid = blockIdx.x, t = threadIdx.x;
    if (bid < 5120) {
        const float* src; ushort* dst; int j;
        if (bid < 4096) { src = x;  dst = xb;  j = bid * 256 + t; }
        else            { src = Wo; dst = Wob; j = (bid - 4096) * 256 + t; }
        float4 v = ((const float4*)src)[j];
        ushort o[4] = { f2bf(v.x), f2bf(v.y), f2bf(v.z), f2bf(v.w) };
        ((uint2*)dst)[j] = *(const uint2*)o;
        return;
    }
    int i = bid - 5120;
    int z = i >> 8, h = (i >> 4) & 15, d0 = (i & 15) * 64;
    const float* W = z == 0 ? Wq : (z == 1 ? Wk : Wv);
    const float* Wh = W + h * DD * HD;
    ushort* Wt = W3T + ((size_t)z * HH + h) * HD * DD;
    #pragma unroll
    for (int s = 0; s < 4; s++) {
        int idx = t + s * 256;
        int d = idx >> 4, e4 = (idx & 15) * 4;
        float4 v = *(const float4*)(Wh + (d0 + d) * HD + e4);
        T[d][e4 + 0] = f2bf(v.x); T[d][e4 + 1] = f2bf(v.y);
        T[d][e4 + 2] = f2bf(v.z); T[d][e4 + 3] = f2bf(v.w);
    }
    __syncthreads();
    #pragma unroll
    for (int s = 0; s < 2; s++) {
        int idx = t + s * 256;
        int e = idx >> 3, d8 = (idx & 7) * 8;
        ushort tmp[8];
        #pragma unroll
        for (int j = 0; j < 8; j++) tmp[j] = T[d8 + j][e];
        *(uint4*)(Wt + e * DD + d0 + d8) = *(uint4*)tmp;
    }
}

// ---- QKV fused: xb[4096,1024] x {Wq,Wk,Wv}T (NT). M-tile 128, N-tile 64, BK=64.
__global__ __launch_bounds__(256) void gemm_qkv(const ushort* __restrict__ xb,
                                                const ushort* __restrict__ W3T,
                                                const float* __restrict__ bq,
                                                const float* __restrict__ bk,
                                                const float* __restrict__ bv,
                                                ushort* __restrict__ qb,
                                                ushort* __restrict__ kb,
                                                ushort* __restrict__ vT) {
    __shared__ ushort Al[128 * 64];      // 16 KB, XOR-swizzled chunks
    __shared__ ushort Bl[3][64 * 64];    // 3 x 8 KB, XOR-swizzled
    int m0 = blockIdx.x * 128, n0 = blockIdx.y * 64;
    int t = threadIdx.x, lane = t & 63, w = t >> 6;
    int wm = w & 1, wn = w >> 1;
    int qm = lane >> 4, lm = lane & 15;

    const ushort* W0 = W3T + (size_t)n0 * DD;
    const ushort* W1 = W3T + (size_t)(HH * HD + n0) * DD;
    const ushort* W2 = W3T + (size_t)(2 * HH * HD + n0) * DD;

    float4v acc[3][4][2] = {};
    for (int k0 = 0; k0 < DD; k0 += 64) {
        __syncthreads();
        #pragma unroll
        for (int s = 0; s < 4; s++) {
            int c = t + s * 256;
            int row = c >> 3;
            int j = (c & 7) ^ (row & 7);
            cp16(xb + (size_t)(m0 + row) * DD + k0 + j * 8, Al + c * 8);
        }
        #pragma unroll
        for (int s = 0; s < 2; s++) {
            int c = t + s * 256;
            int row = c >> 3;
            int j = (c & 7) ^ (row & 7);
            cp16(W0 + (size_t)row * DD + k0 + j * 8, Bl[0] + c * 8);
            cp16(W1 + (size_t)row * DD + k0 + j * 8, Bl[1] + c * 8);
            cp16(W2 + (size_t)row * DD + k0 + j * 8, Bl[2] + c * 8);
        }
        __syncthreads();
        #pragma unroll
        for (int h2 = 0; h2 < 2; h2++) {
            int sw = ((((h2 << 2) | qm) ^ (lm & 7)) << 3);
            short8 a[4];
            #pragma unroll
            for (int i = 0; i < 4; i++)
                a[i] = *(const short8*)(Al + ((wm * 64 + i * 16 + lm) << 6) + sw);
            #pragma unroll
            for (int z = 0; z < 3; z++) {
                short8 b0 = *(const short8*)(Bl[z] + ((wn * 32 + lm) << 6) + sw);
                short8 b1 = *(const short8*)(Bl[z] + ((wn * 32 + 16 + lm) << 6) + sw);
                if (z == 2) {
                    #pragma unroll
                    for (int i = 0; i < 4; i++) {
                        acc[2][i][0] = __builtin_amdgcn_mfma_f32_16x16x32_bf16(a[i], b0, acc[2][i][0], 0, 0, 0);
                        acc[2][i][1] = __builtin_amdgcn_mfma_f32_16x16x32_bf16(a[i], b1, acc[2][i][1], 0, 0, 0);
                    }
                } else {   // swapped: D rows = n (4 consec per lane), cols = m
                    #pragma unroll
                    for (int i = 0; i < 4; i++) {
                        acc[z][i][0] = __builtin_amdgcn_mfma_f32_16x16x32_bf16(b0, a[i], acc[z][i][0], 0, 0, 0);
                        acc[z][i][1] = __builtin_amdgcn_mfma_f32_16x16x32_bf16(b1, a[i], acc[z][i][1], 0, 0, 0);
                    }
                }
            }
        }
    }
    #pragma unroll
    for (int z = 0; z < 2; z++) {
        const float* bias = z == 0 ? bq : bk;
        ushort* Out = z == 0 ? qb : kb;
        float sc = z == 0 ? QSCALE : 1.0f;
        #pragma unroll
        for (int j = 0; j < 2; j++) {
            int nb = n0 + wn * 32 + j * 16 + qm * 4;
            float4 b4 = *(const float4*)(bias + nb);
            #pragma unroll
            for (int i = 0; i < 4; i++) {
                int m = m0 + wm * 64 + i * 16 + lm;
                uint2 o2;
                o2.x = pack_bf2((acc[z][i][j][0] + b4.x) * sc, (acc[z][i][j][1] + b4.y) * sc);
                o2.y = pack_bf2((acc[z][i][j][2] + b4.z) * sc, (acc[z][i][j][3] + b4.w) * sc);
                *(uint2*)(Out + (size_t)m * DD + nb) = o2;
            }
        }
    }
    #pragma unroll
    for (int j = 0; j < 2; j++) {
        int n = n0 + wn * 32 + j * 16 + lm;
        int h = n >> 6, e = n & 63;
        float bb = bv[n];
        #pragma unroll
        for (int i = 0; i < 4; i++) {
            int m = m0 + wm * 64 + i * 16 + qm * 4;
            int b_ = m >> 11, s = m & (SS - 1);
            uint2 o2;
            o2.x = pack_bf2(acc[2][i][j][0] + bb, acc[2][i][j][1] + bb);
            o2.y = pack_bf2(acc[2][i][j][2] + bb, acc[2][i][j][3] + bb);
            *(uint2*)(vT + ((size_t)(b_ * HH + h) * HD + e) * SS + s) = o2;
        }
    }
}

// -------- flash attention (causal), S^T form, static-max softmax.
// -------- 128-thread blocks (2 waves), wave owns 32 q-rows: each K/V ds_read feeds 2 MFMAs.
// -------- q-tile 64, LDS 40960B -> 4 blocks/CU. Grid 1024 quarter-balanced qt map:
// -------- batches of 256 blocks carry qt = 31-j, 16+j, 15-j, j (66 iter-units per CU).
__global__ __launch_bounds__(128, 2) void attn(const ushort* __restrict__ Q,
                                               const ushort* __restrict__ K,
                                               const ushort* __restrict__ VT,
                                               ushort* __restrict__ O) {
    __shared__ ushort Ql[64 * 64];            // Q tile (swizzled); wave's 32 rows reused as P
    __shared__ ushort Kl[2][64 * 64];         // swizzled, 8 KB each
    __shared__ ushort Vl[2][64 * 64];
    int id = blockIdx.x;
    int bh = id & 31;
    int j5 = (id >> 5) & 7;
    int quad = id >> 8;
    int qt = (quad == 0) ? (31 - j5) : (quad == 1) ? (16 + j5)
           : (quad == 2) ? (15 - j5) : j5;
    int b = bh >> 4, h = bh & 15;
    int m0 = qt * 64;
    const ushort* Qp = Q + (size_t)b * SS * DD + h * HD;
    const ushort* Kp = K + (size_t)b * SS * DD + h * HD;
    const ushort* Vp = VT + (size_t)bh * HD * SS;
    int t = threadIdx.x, lane = t & 63, w = t >> 6;      // w in [0,2)
    int qm = lane >> 4, lm = lane & 15;
    int swz = ((qm ^ (lm & 7)) << 3);        // kc=0 frag chunk offset (ushorts)
    int swz1 = (((4 | qm) ^ (lm & 7)) << 3); // kc=1

    // stage Q + K/V tile 0 via cp16 (XOR-swizzled global chunk, linear LDS dest)
    #pragma unroll
    for (int s2 = 0; s2 < 4; s2++) {
        int c = t + s2 * 128;
        int row = c >> 3, sj = (c & 7) ^ (row & 7);
        cp16(Qp + (size_t)(m0 + row) * DD + sj * 8, Ql + c * 8);
        cp16(Kp + (size_t)row * DD + sj * 8, Kl[0] + c * 8);
        cp16(Vp + (size_t)row * SS + sj * 8, Vl[0] + c * 8);
    }
    __syncthreads();

    short8 qf[2][2];   // [q-group g][kc] B-frags hoisted; own Ql rows become P
    #pragma unroll
    for (int g = 0; g < 2; g++) {
        int rb = (w * 32 + g * 16 + lm) << 6;
        qf[g][0] = *(const short8*)(Ql + rb + swz);
        qf[g][1] = *(const short8*)(Ql + rb + swz1);
    }

    float4v o[4][2] = {};     // [e-group jn][q-group g]
    float li[2] = {0.f, 0.f};
    int cur = 0;

    for (int jt = 0; jt <= qt; jt++) {
        if (jt) __syncthreads();    // prev prefetch drained (compiler vmcnt before barrier);
                                    // all waves done reading cur^1
        if (jt < qt) {              // prefetch next tile into cur^1, async
            int nn = (jt + 1) * 64;
            #pragma unroll
            for (int s2 = 0; s2 < 4; s2++) {
                int c = t + s2 * 128;
                int row = c >> 3, sj = (c & 7) ^ (row & 7);
                cp16(Kp + (size_t)(nn + row) * DD + sj * 8, Kl[cur ^ 1] + c * 8);
                cp16(Vp + (size_t)row * SS + nn + sj * 8, Vl[cur ^ 1] + c * 8);
            }
        }

        // St = K·Q^T: lane holds k = j*16+qm*4+r, q = g*16+lm (q prescaled by QSCALE).
        // Each ak read feeds both q-groups (2 MFMAs).
        float4v s[4][2] = {};
        __builtin_amdgcn_s_setprio(1);
        #pragma unroll
        for (int j = 0; j < 4; j++) {
            short8 ak0 = *(const short8*)(Kl[cur] + ((j * 16 + lm) << 6) + swz);
            short8 ak1 = *(const short8*)(Kl[cur] + ((j * 16 + lm) << 6) + swz1);
            #pragma unroll
            for (int g = 0; g < 2; g++) {
                s[j][g] = __builtin_amdgcn_mfma_f32_16x16x32_bf16(ak0, qf[g][0], s[j][g], 0, 0, 0);
                s[j][g] = __builtin_amdgcn_mfma_f32_16x16x32_bf16(ak1, qf[g][1], s[j][g], 0, 0, 0);
            }
        }
        __builtin_amdgcn_s_setprio(0);
        if (jt == qt) {   // diagonal tile: mask k > q
            #pragma unroll
            for (int g = 0; g < 2; g++) {
                int qg = m0 + w * 32 + g * 16 + lm;
                #pragma unroll
                for (int j = 0; j < 4; j++)
                    #pragma unroll
                    for (int r = 0; r < 4; r++)
                        if (jt * 64 + j * 16 + qm * 4 + r > qg) s[j][g][r] = -__builtin_inff();
            }
        }
        // p = exp2(s); per-lane li; write P (packed bf16) to own Ql rows (swizzled)
        #pragma unroll
        for (int g = 0; g < 2; g++) {
            int rb = (w * 32 + g * 16 + lm) << 6;
            #pragma unroll
            for (int j = 0; j < 4; j++) {
                float p0 = __builtin_amdgcn_exp2f(s[j][g][0]);
                float p1 = __builtin_amdgcn_exp2f(s[j][g][1]);
                float p2 = __builtin_amdgcn_exp2f(s[j][g][2]);
                float p3 = __builtin_amdgcn_exp2f(s[j][g][3]);
                li[g] += (p0 + p1) + (p2 + p3);
                uint2 u; u.x = pack_bf2(p0, p1); u.y = pack_bf2(p2, p3);
                int pc = (2 * j + (qm >> 1)) ^ (lm & 7);
                *(uint2*)(Ql + rb + (pc << 3) + (qm & 1) * 4) = u;
            }
        }
        asm volatile("s_waitcnt lgkmcnt(0)" ::: "memory");  // P RAW (wave-internal)

        // O += V^T·P^T: A = V rows (e), B = P (n=q) -> D rows = e, cols = q.
        // Each av read feeds both q-groups (2 MFMAs).
        __builtin_amdgcn_s_setprio(1);
        #pragma unroll
        for (int kc = 0; kc < 2; kc++) {
            short8 ap[2];
            #pragma unroll
            for (int g = 0; g < 2; g++)
                ap[g] = *(const short8*)(Ql + ((w * 32 + g * 16 + lm) << 6) + (kc ? swz1 : swz));
            #pragma unroll
            for (int jn = 0; jn < 4; jn++) {
                short8 av = *(const short8*)(Vl[cur] + ((jn * 16 + lm) << 6) + (kc ? swz1 : swz));
                #pragma unroll
                for (int g = 0; g < 2; g++)
                    o[jn][g] = __builtin_amdgcn_mfma_f32_16x16x32_bf16(av, ap[g], o[jn][g], 0, 0, 0);
            }
        }
        __builtin_amdgcn_s_setprio(0);
        cur ^= 1;
    }
    #pragma unroll
    for (int g = 0; g < 2; g++) {
        float l = li[g];
        l += __shfl_xor(l, 16, 64);
        l += __shfl_xor(l, 32, 64);
        float inv = 1.f / l;
        int qg = m0 + w * 32 + g * 16 + lm;
        ushort* Ob = O + ((size_t)b * SS + qg) * DD + h * HD;
        #pragma unroll
        for (int jn = 0; jn < 4; jn++) {
            uint2 u;
            u.x = pack_bf2(o[jn][g][0] * inv, o[jn][g][1] * inv);
            u.y = pack_bf2(o[jn][g][2] * inv, o[jn][g][3] * inv);
            *(uint2*)(Ob + jn * 16 + qm * 4) = u;
        }
    }
}

// ---- out proj: wvb[4096,1024] x Wob^T (NT, 128x64, BK=64, swizzled; 16B fp32 stores) ----
__global__ __launch_bounds__(256) void gemm_out(const ushort* __restrict__ X,
                                                const ushort* __restrict__ Wob,
                                                const float* __restrict__ bo,
                                                float* __restrict__ Out) {
    __shared__ ushort Al[128 * 64];
    __shared__ ushort Bl[64 * 64];
    int m0 = blockIdx.x * 128, n0 = blockIdx.y * 64;
    int t = threadIdx.x, lane = t & 63, w = t >> 6;
    int wm = w & 1, wn = w >> 1;
    int qm = lane >> 4, lm = lane & 15;

    float4v acc[4][2] = {};
    for (int k0 = 0; k0 < DD; k0 += 64) {
        __syncthreads();
        #pragma unroll
        for (int s = 0; s < 4; s++) {
            int c = t + s * 256;
            int row = c >> 3;
            int j = (c & 7) ^ (row & 7);
            cp16(X + (size_t)(m0 + row) * DD + k0 + j * 8, Al + c * 8);
        }
        #pragma unroll
        for (int s = 0; s < 2; s++) {
            int c = t + s * 256;
            int row = c >> 3;
            int j = (c & 7) ^ (row & 7);
            cp16(Wob + (size_t)(n0 + row) * DD + k0 + j * 8, Bl + c * 8);
        }
        __syncthreads();
        #pragma unroll
        for (int h2 = 0; h2 < 2; h2++) {
            int sw = ((((h2 << 2) | qm) ^ (lm & 7)) << 3);
            short8 a[4], b[2];
            #pragma unroll
            for (int i = 0; i < 4; i++)
                a[i] = *(const short8*)(Al + ((wm * 64 + i * 16 + lm) << 6) + sw);
            #pragma unroll
            for (int j = 0; j < 2; j++)
                b[j] = *(const short8*)(Bl + ((wn * 32 + j * 16 + lm) << 6) + sw);
            #pragma unroll
            for (int i = 0; i < 4; i++)
                #pragma unroll
                for (int j = 0; j < 2; j++)
                    acc[i][j] = __builtin_amdgcn_mfma_f32_16x16x32_bf16(b[j], a[i], acc[i][j], 0, 0, 0);
        }
    }
    #pragma unroll
    for (int j = 0; j < 2; j++) {
        int nb = n0 + wn * 32 + j * 16 + qm * 4;
        float4 b4 = *(const float4*)(bo + nb);
        #pragma unroll
        for (int i = 0; i < 4; i++) {
            int m = m0 + wm * 64 + i * 16 + lm;
            float4 st;
            st.x = acc[i][j][0] + b4.x;
            st.y = acc[i][j][1] + b4.y;
            st.z = acc[i][j][2] + b4.z;
            st.w = acc[i][j][3] + b4.w;
            *(float4*)(Out + (size_t)m * DD + nb) = st;
        }
    }
}

extern "C" void kernel_launch(void* const* d_in, const int* in_sizes, int n_in,
                              void* d_out, int out_size, void* d_ws, size_t ws_size,
                              hipStream_t stream) {
    const float* x   = (const float*)d_in[0];
    const float* Wq  = (const float*)d_in[1];
    const float* bq  = (const float*)d_in[2];
    const float* Wk  = (const float*)d_in[3];
    const float* bk  = (const float*)d_in[4];
    const float* Wv_ = (const float*)d_in[5];
    const float* bv  = (const float*)d_in[6];
    const float* Wo  = (const float*)d_in[7];
    const float* bo  = (const float*)d_in[8];
    float* out = (float*)d_out;

    ushort* xb  = (ushort*)d_ws;
    ushort* W3T = xb  + (size_t)BB * SS * DD;
    ushort* Wob = W3T + (size_t)3 * HH * HD * DD;
    ushort* qb  = Wob + (size_t)DD * DD;
    ushort* kb  = qb + (size_t)BB * SS * DD;
    ushort* vT  = kb + (size_t)BB * SS * DD;
    ushort* wvb = vT + (size_t)BB * SS * DD;

    prep<<<dim3(5888), 256, 0, stream>>>(x, Wo, Wq, Wk, Wv_, xb, Wob, W3T);
    gemm_qkv<<<dim3(32, 16), 256, 0, stream>>>(xb, W3T, bq, bk, bv, qb, kb, vT);
    attn<<<dim3(1024), 128, 0, stream>>>(qb, kb, vT, wvb);
    gemm_out<<<dim3(32, 16), 256, 0, stream>>>(wvb, Wob, bo, out);
}

// Round 3
// 175.143 us; speedup vs baseline: 1.0716x; 1.0716x over previous
//
#include <hip/hip_runtime.h>

// Attention_77730318123148 — B=2,S=2048,D=1024,H=16,HD=64. fp32 I/O, bf16 MFMA compute.
// R14: attn = R12 occupancy x R13 reuse. 256-thr blocks, 64-row q-tile, grid 1024
// (quarter-balanced qt map). Waves pair-split by jt parity: pair A (w0,w1) even tiles,
// pair B (w2,w3) odd tiles; each wave owns 32 q-rows (2 q-frags) so every K/V ds_read
// feeds 2 MFMAs. Single-buffered K/V per pair (4x8KB) + 128-row QP (Q then P) = 48KB
// -> 3 blocks/CU (12 waves). Static-max softmax => pair partials (O, li) combine by
// addition through LDS at the end. gemm_qkv / gemm_out / prep unchanged.

#define DD 1024
#define SS 2048
#define BB 2
#define HH 16
#define HD 64
#define QSCALE 0.18033688011112042f   // 0.125 * log2(e)

typedef __attribute__((ext_vector_type(8))) short short8;   // 8 bf16 (A/B frag)
typedef __attribute__((ext_vector_type(4))) float float4v;  // C/D frag
typedef unsigned short ushort;
typedef unsigned int uint;

__device__ inline ushort f2bf(float f) {       // RNE (input conversion fidelity)
    union { float f; uint i; } v; v.f = f;
    uint r = v.i + 0x7FFF + ((v.i >> 16) & 1);
    return (ushort)(r >> 16);
}
#if __has_builtin(__builtin_amdgcn_cvt_pk_bf16_f32)
typedef __bf16 bf16x2 __attribute__((ext_vector_type(2)));
__device__ inline uint pack_bf2(float a, float b) {   // 1 inst, RNE
    union { bf16x2 v; uint u; } c;
    c.v = __builtin_amdgcn_cvt_pk_bf16_f32(a, b);
    return c.u;
}
#else
__device__ inline uint pack_bf2(float a, float b) {   // fallback: round-half-up
    union { float f; uint i; } x, y; x.f = a; y.f = b;
    return ((x.i + 0x8000u) >> 16) | (((y.i + 0x8000u) >> 16) << 16);
}
#endif

__device__ __forceinline__ void cp16(const ushort* g, ushort* l) {
    __builtin_amdgcn_global_load_lds((const __attribute__((address_space(1))) void*)g,
                                     (__attribute__((address_space(3))) void*)l,
                                     16, 0, 0);
}

// ---------------- prep: cvt x (4096 blk) | cvt Wo (1024 blk) | transpose W3 (768 blk) ----
__global__ __launch_bounds__(256) void prep(const float* __restrict__ x,
                                            const float* __restrict__ Wo,
                                            const float* __restrict__ Wq,
                                            const float* __restrict__ Wk,
                                            const float* __restrict__ Wv,
                                            ushort* __restrict__ xb,
                                            ushort* __restrict__ Wob,
                                            ushort* __restrict__ W3T) {
    __shared__ ushort T[64][65];
    int bid = blockIdx.x, t = threadIdx.x;
    if (bid < 5120) {
        const float* src; ushort* dst; int j;
        if (bid < 4096) { src = x;  dst = xb;  j = bid * 256 + t; }
        else            { src = Wo; dst = Wob; j = (bid - 4096) * 256 + t; }
        float4 v = ((const float4*)src)[j];
        ushort o[4] = { f2bf(v.x), f2bf(v.y), f2bf(v.z), f2bf(v.w) };
        ((uint2*)dst)[j] = *(const uint2*)o;
        return;
    }
    int i = bid - 5120;
    int z = i >> 8, h = (i >> 4) & 15, d0 = (i & 15) * 64;
    const float* W = z == 0 ? Wq : (z == 1 ? Wk : Wv);
    const float* Wh = W + h * DD * HD;
    ushort* Wt = W3T + ((size_t)z * HH + h) * HD * DD;
    #pragma unroll
    for (int s = 0; s < 4; s++) {
        int idx = t + s * 256;
        int d = idx >> 4, e4 = (idx & 15) * 4;
        float4 v = *(const float4*)(Wh + (d0 + d) * HD + e4);
        T[d][e4 + 0] = f2bf(v.x); T[d][e4 + 1] = f2bf(v.y);
        T[d][e4 + 2] = f2bf(v.z); T[d][e4 + 3] = f2bf(v.w);
    }
    __syncthreads();
    #pragma unroll
    for (int s = 0; s < 2; s++) {
        int idx = t + s * 256;
        int e = idx >> 3, d8 = (idx & 7) * 8;
        ushort tmp[8];
        #pragma unroll
        for (int j = 0; j < 8; j++) tmp[j] = T[d8 + j][e];
        *(uint4*)(Wt + e * DD + d0 + d8) = *(uint4*)tmp;
    }
}

// ---- QKV fused: xb[4096,1024] x {Wq,Wk,Wv}T (NT). M-tile 128, N-tile 64, BK=64.
__global__ __launch_bounds__(256) void gemm_qkv(const ushort* __restrict__ xb,
                                                const ushort* __restrict__ W3T,
                                                const float* __restrict__ bq,
                                                const float* __restrict__ bk,
                                                const float* __restrict__ bv,
                                                ushort* __restrict__ qb,
                                                ushort* __restrict__ kb,
                                                ushort* __restrict__ vT) {
    __shared__ ushort Al[128 * 64];      // 16 KB, XOR-swizzled chunks
    __shared__ ushort Bl[3][64 * 64];    // 3 x 8 KB, XOR-swizzled
    int m0 = blockIdx.x * 128, n0 = blockIdx.y * 64;
    int t = threadIdx.x, lane = t & 63, w = t >> 6;
    int wm = w & 1, wn = w >> 1;
    int qm = lane >> 4, lm = lane & 15;

    const ushort* W0 = W3T + (size_t)n0 * DD;
    const ushort* W1 = W3T + (size_t)(HH * HD + n0) * DD;
    const ushort* W2 = W3T + (size_t)(2 * HH * HD + n0) * DD;

    float4v acc[3][4][2] = {};
    for (int k0 = 0; k0 < DD; k0 += 64) {
        __syncthreads();
        #pragma unroll
        for (int s = 0; s < 4; s++) {
            int c = t + s * 256;
            int row = c >> 3;
            int j = (c & 7) ^ (row & 7);
            cp16(xb + (size_t)(m0 + row) * DD + k0 + j * 8, Al + c * 8);
        }
        #pragma unroll
        for (int s = 0; s < 2; s++) {
            int c = t + s * 256;
            int row = c >> 3;
            int j = (c & 7) ^ (row & 7);
            cp16(W0 + (size_t)row * DD + k0 + j * 8, Bl[0] + c * 8);
            cp16(W1 + (size_t)row * DD + k0 + j * 8, Bl[1] + c * 8);
            cp16(W2 + (size_t)row * DD + k0 + j * 8, Bl[2] + c * 8);
        }
        __syncthreads();
        #pragma unroll
        for (int h2 = 0; h2 < 2; h2++) {
            int sw = ((((h2 << 2) | qm) ^ (lm & 7)) << 3);
            short8 a[4];
            #pragma unroll
            for (int i = 0; i < 4; i++)
                a[i] = *(const short8*)(Al + ((wm * 64 + i * 16 + lm) << 6) + sw);
            #pragma unroll
            for (int z = 0; z < 3; z++) {
                short8 b0 = *(const short8*)(Bl[z] + ((wn * 32 + lm) << 6) + sw);
                short8 b1 = *(const short8*)(Bl[z] + ((wn * 32 + 16 + lm) << 6) + sw);
                if (z == 2) {
                    #pragma unroll
                    for (int i = 0; i < 4; i++) {
                        acc[2][i][0] = __builtin_amdgcn_mfma_f32_16x16x32_bf16(a[i], b0, acc[2][i][0], 0, 0, 0);
                        acc[2][i][1] = __builtin_amdgcn_mfma_f32_16x16x32_bf16(a[i], b1, acc[2][i][1], 0, 0, 0);
                    }
                } else {   // swapped: D rows = n (4 consec per lane), cols = m
                    #pragma unroll
                    for (int i = 0; i < 4; i++) {
                        acc[z][i][0] = __builtin_amdgcn_mfma_f32_16x16x32_bf16(b0, a[i], acc[z][i][0], 0, 0, 0);
                        acc[z][i][1] = __builtin_amdgcn_mfma_f32_16x16x32_bf16(b1, a[i], acc[z][i][1], 0, 0, 0);
                    }
                }
            }
        }
    }
    #pragma unroll
    for (int z = 0; z < 2; z++) {
        const float* bias = z == 0 ? bq : bk;
        ushort* Out = z == 0 ? qb : kb;
        float sc = z == 0 ? QSCALE : 1.0f;
        #pragma unroll
        for (int j = 0; j < 2; j++) {
            int nb = n0 + wn * 32 + j * 16 + qm * 4;
            float4 b4 = *(const float4*)(bias + nb);
            #pragma unroll
            for (int i = 0; i < 4; i++) {
                int m = m0 + wm * 64 + i * 16 + lm;
                uint2 o2;
                o2.x = pack_bf2((acc[z][i][j][0] + b4.x) * sc, (acc[z][i][j][1] + b4.y) * sc);
                o2.y = pack_bf2((acc[z][i][j][2] + b4.z) * sc, (acc[z][i][j][3] + b4.w) * sc);
                *(uint2*)(Out + (size_t)m * DD + nb) = o2;
            }
        }
    }
    #pragma unroll
    for (int j = 0; j < 2; j++) {
        int n = n0 + wn * 32 + j * 16 + lm;
        int h = n >> 6, e = n & 63;
        float bb = bv[n];
        #pragma unroll
        for (int i = 0; i < 4; i++) {
            int m = m0 + wm * 64 + i * 16 + qm * 4;
            int b_ = m >> 11, s = m & (SS - 1);
            uint2 o2;
            o2.x = pack_bf2(acc[2][i][j][0] + bb, acc[2][i][j][1] + bb);
            o2.y = pack_bf2(acc[2][i][j][2] + bb, acc[2][i][j][3] + bb);
            *(uint2*)(vT + ((size_t)(b_ * HH + h) * HD + e) * SS + s) = o2;
        }
    }
}

// -------- flash attention (causal), S^T form, static-max softmax, jt-parity pair split.
// -------- LDS carve (ushort offsets): QP[0..8192) 16KB (Q rows 0-63, then P rows 0-127),
// -------- KA@8192 VA@12288 KB@16384 VB@20480 (8KB each). Total 48KB -> 3 blocks/CU.
__global__ __launch_bounds__(256, 3) void attn(const ushort* __restrict__ Q,
                                               const ushort* __restrict__ K,
                                               const ushort* __restrict__ VT,
                                               ushort* __restrict__ O) {
    __shared__ ushort LB[24576];          // 48 KB
    ushort* QP = LB;
    int id = blockIdx.x;
    int bh = id & 31;
    int j5 = (id >> 5) & 7;
    int quad = id >> 8;
    int qt = (quad == 0) ? (31 - j5) : (quad == 1) ? (16 + j5)
           : (quad == 2) ? (15 - j5) : j5;
    int b = bh >> 4, h = bh & 15;
    int m0 = qt * 64;
    const ushort* Qp = Q + (size_t)b * SS * DD + h * HD;
    const ushort* Kp = K + (size_t)b * SS * DD + h * HD;
    const ushort* Vp = VT + (size_t)bh * HD * SS;
    int t = threadIdx.x, lane = t & 63, w = t >> 6;      // w in [0,4)
    int pr = w >> 1, wq = w & 1;                         // pair, q-half
    int qm = lane >> 4, lm = lane & 15;
    int swz = ((qm ^ (lm & 7)) << 3);        // kc=0 frag chunk offset (ushorts)
    int swz1 = (((4 | qm) ^ (lm & 7)) << 3); // kc=1
    int c0 = t, c1 = t + 256;
    int r0 = c0 >> 3, s0 = (c0 & 7) ^ (r0 & 7);
    int r1 = c1 >> 3, s1 = (c1 & 7) ^ (r1 & 7);

    // stage Q (rows 0-63 of QP) + tile0 -> A bufs (+ tile1 -> B bufs if present)
    cp16(Qp + (size_t)(m0 + r0) * DD + s0 * 8, QP + c0 * 8);
    cp16(Qp + (size_t)(m0 + r1) * DD + s1 * 8, QP + c1 * 8);
    cp16(Kp + (size_t)r0 * DD + s0 * 8, LB + 8192 + c0 * 8);
    cp16(Kp + (size_t)r1 * DD + s1 * 8, LB + 8192 + c1 * 8);
    cp16(Vp + (size_t)r0 * SS + s0 * 8, LB + 12288 + c0 * 8);
    cp16(Vp + (size_t)r1 * SS + s1 * 8, LB + 12288 + c1 * 8);
    if (qt >= 1) {
        cp16(Kp + (size_t)(64 + r0) * DD + s0 * 8, LB + 16384 + c0 * 8);
        cp16(Kp + (size_t)(64 + r1) * DD + s1 * 8, LB + 16384 + c1 * 8);
        cp16(Vp + (size_t)r0 * SS + 64 + s0 * 8, LB + 20480 + c0 * 8);
        cp16(Vp + (size_t)r1 * SS + 64 + s1 * 8, LB + 20480 + c1 * 8);
    }
    __syncthreads();                       // all staging drained & visible

    short8 qf[2][2];   // [q-group g][kc] from Q rows (wq*32 + g*16 + lm)
    #pragma unroll
    for (int g = 0; g < 2; g++) {
        int rb = (wq * 32 + g * 16 + lm) << 6;
        qf[g][0] = *(const short8*)(QP + rb + swz);
        qf[g][1] = *(const short8*)(QP + rb + swz1);
    }
    __syncthreads();   // REQUIRED: pair-A P-writes (rows 0-63) clobber pair-B's Q source

    ushort* Kb = LB + 8192 + pr * 8192;    // KA or KB
    ushort* Vb = LB + 12288 + pr * 8192;   // VA or VB
    float4v o[4][2] = {};     // [e-group jn][q-group g]
    float li[2] = {0.f, 0.f};
    int nss = (qt + 2) >> 1;

    for (int ss = 0; ss < nss; ss++) {
        int myjt = 2 * ss + pr;
        if (myjt <= qt) {
            // St = K·Q^T: lane holds k = j*16+qm*4+r, q = g*16+lm (q prescaled by QSCALE)
            float4v s[4][2] = {};
            __builtin_amdgcn_s_setprio(1);
            #pragma unroll
            for (int j = 0; j < 4; j++) {
                short8 ak0 = *(const short8*)(Kb + ((j * 16 + lm) << 6) + swz);
                short8 ak1 = *(const short8*)(Kb + ((j * 16 + lm) << 6) + swz1);
                #pragma unroll
                for (int g = 0; g < 2; g++) {
                    s[j][g] = __builtin_amdgcn_mfma_f32_16x16x32_bf16(ak0, qf[g][0], s[j][g], 0, 0, 0);
                    s[j][g] = __builtin_amdgcn_mfma_f32_16x16x32_bf16(ak1, qf[g][1], s[j][g], 0, 0, 0);
                }
            }
            __builtin_amdgcn_s_setprio(0);
            if (myjt == qt) {   // diagonal tile: mask k > q
                #pragma unroll
                for (int g = 0; g < 2; g++) {
                    int qg = m0 + wq * 32 + g * 16 + lm;
                    #pragma unroll
                    for (int j = 0; j < 4; j++)
                        #pragma unroll
                        for (int r = 0; r < 4; r++)
                            if (myjt * 64 + j * 16 + qm * 4 + r > qg) s[j][g][r] = -__builtin_inff();
                }
            }
            // p = exp2(s); per-lane li; write P (packed bf16) to own QP rows (w*32..)
            #pragma unroll
            for (int g = 0; g < 2; g++) {
                int rb = (w * 32 + g * 16 + lm) << 6;
                #pragma unroll
                for (int j = 0; j < 4; j++) {
                    float p0 = __builtin_amdgcn_exp2f(s[j][g][0]);
                    float p1 = __builtin_amdgcn_exp2f(s[j][g][1]);
                    float p2 = __builtin_amdgcn_exp2f(s[j][g][2]);
                    float p3 = __builtin_amdgcn_exp2f(s[j][g][3]);
                    li[g] += (p0 + p1) + (p2 + p3);
                    uint2 u; u.x = pack_bf2(p0, p1); u.y = pack_bf2(p2, p3);
                    int pc = (2 * j + (qm >> 1)) ^ (lm & 7);
                    *(uint2*)(QP + rb + (pc << 3) + (qm & 1) * 4) = u;
                }
            }
            asm volatile("s_waitcnt lgkmcnt(0)" ::: "memory");  // P RAW (wave-internal)

            // O += V^T·P^T: A = V rows (e), B = P (n=q) -> D rows = e, cols = q
            __builtin_amdgcn_s_setprio(1);
            #pragma unroll
            for (int kc = 0; kc < 2; kc++) {
                short8 ap[2];
                #pragma unroll
                for (int g = 0; g < 2; g++)
                    ap[g] = *(const short8*)(QP + ((w * 32 + g * 16 + lm) << 6) + (kc ? swz1 : swz));
                #pragma unroll
                for (int jn = 0; jn < 4; jn++) {
                    short8 av = *(const short8*)(Vb + ((jn * 16 + lm) << 6) + (kc ? swz1 : swz));
                    #pragma unroll
                    for (int g = 0; g < 2; g++)
                        o[jn][g] = __builtin_amdgcn_mfma_f32_16x16x32_bf16(av, ap[g], o[jn][g], 0, 0, 0);
                }
            }
            __builtin_amdgcn_s_setprio(0);
        }
        __syncthreads();               // both pairs done reading their buffers
        int nx = 2 * ss + 2;
        if (nx <= qt) {                // stage next even tile -> A bufs
            cp16(Kp + (size_t)(nx * 64 + r0) * DD + s0 * 8, LB + 8192 + c0 * 8);
            cp16(Kp + (size_t)(nx * 64 + r1) * DD + s1 * 8, LB + 8192 + c1 * 8);
            cp16(Vp + (size_t)r0 * SS + nx * 64 + s0 * 8, LB + 12288 + c0 * 8);
            cp16(Vp + (size_t)r1 * SS + nx * 64 + s1 * 8, LB + 12288 + c1 * 8);
        }
        if (nx + 1 <= qt) {            // stage next odd tile -> B bufs
            cp16(Kp + (size_t)((nx + 1) * 64 + r0) * DD + s0 * 8, LB + 16384 + c0 * 8);
            cp16(Kp + (size_t)((nx + 1) * 64 + r1) * DD + s1 * 8, LB + 16384 + c1 * 8);
            cp16(Vp + (size_t)r0 * SS + (nx + 1) * 64 + s0 * 8, LB + 20480 + c0 * 8);
            cp16(Vp + (size_t)r1 * SS + (nx + 1) * 64 + s1 * 8, LB + 20480 + c1 * 8);
        }
        __syncthreads();               // staged tiles ready (vmcnt drained here)
    }

    // combine pair partials: O = O_A + O_B, li = li_A + li_B (static-max softmax)
    float* cb = (float*)(LB + 8192);       // [2][64][32] floats = 16 KB (over KA+VA)
    float* cl = (float*)(LB + 16384);      // [2][64][2]  floats (over KB start)
    if (pr == 1) {
        float* dst = cb + ((size_t)(wq * 64 + lane)) * 32;
        #pragma unroll
        for (int jn = 0; jn < 4; jn++)
            #pragma unroll
            for (int g = 0; g < 2; g++) {
                int slot = jn * 2 + g;
                *(float4v*)(dst + ((slot ^ (lane & 7)) << 2)) = o[jn][g];
            }
        cl[(wq * 64 + lane) * 2 + 0] = li[0];
        cl[(wq * 64 + lane) * 2 + 1] = li[1];
    }
    __syncthreads();
    if (pr == 0) {
        float* src = cb + ((size_t)(wq * 64 + lane)) * 32;
        #pragma unroll
        for (int jn = 0; jn < 4; jn++)
            #pragma unroll
            for (int g = 0; g < 2; g++) {
                int slot = jn * 2 + g;
                float4v v = *(const float4v*)(src + ((slot ^ (lane & 7)) << 2));
                o[jn][g] += v;
            }
        li[0] += cl[(wq * 64 + lane) * 2 + 0];
        li[1] += cl[(wq * 64 + lane) * 2 + 1];
        #pragma unroll
        for (int g = 0; g < 2; g++) {
            float l = li[g];
            l += __shfl_xor(l, 16, 64);
            l += __shfl_xor(l, 32, 64);
            float inv = 1.f / l;
            int qg = m0 + wq * 32 + g * 16 + lm;
            ushort* Ob = O + ((size_t)b * SS + qg) * DD + h * HD;
            #pragma unroll
            for (int jn = 0; jn < 4; jn++) {
                uint2 u;
                u.x = pack_bf2(o[jn][g][0] * inv, o[jn][g][1] * inv);
                u.y = pack_bf2(o[jn][g][2] * inv, o[jn][g][3] * inv);
                *(uint2*)(Ob + jn * 16 + qm * 4) = u;
            }
        }
    }
}

// ---- out proj: wvb[4096,1024] x Wob^T (NT, 128x64, BK=64, swizzled; 16B fp32 stores) ----
__global__ __launch_bounds__(256) void gemm_out(const ushort* __restrict__ X,
                                                const ushort* __restrict__ Wob,
                                                const float* __restrict__ bo,
                                                float* __restrict__ Out) {
    __shared__ ushort Al[128 * 64];
    __shared__ ushort Bl[64 * 64];
    int m0 = blockIdx.x * 128, n0 = blockIdx.y * 64;
    int t = threadIdx.x, lane = t & 63, w = t >> 6;
    int wm = w & 1, wn = w >> 1;
    int qm = lane >> 4, lm = lane & 15;

    float4v acc[4][2] = {};
    for (int k0 = 0; k0 < DD; k0 += 64) {
        __syncthreads();
        #pragma unroll
        for (int s = 0; s < 4; s++) {
            int c = t + s * 256;
            int row = c >> 3;
            int j = (c & 7) ^ (row & 7);
            cp16(X + (size_t)(m0 + row) * DD + k0 + j * 8, Al + c * 8);
        }
        #pragma unroll
        for (int s = 0; s < 2; s++) {
            int c = t + s * 256;
            int row = c >> 3;
            int j = (c & 7) ^ (row & 7);
            cp16(Wob + (size_t)(n0 + row) * DD + k0 + j * 8, Bl + c * 8);
        }
        __syncthreads();
        #pragma unroll
        for (int h2 = 0; h2 < 2; h2++) {
            int sw = ((((h2 << 2) | qm) ^ (lm & 7)) << 3);
            short8 a[4], b[2];
            #pragma unroll
            for (int i = 0; i < 4; i++)
                a[i] = *(const short8*)(Al + ((wm * 64 + i * 16 + lm) << 6) + sw);
            #pragma unroll
            for (int j = 0; j < 2; j++)
                b[j] = *(const short8*)(Bl + ((wn * 32 + j * 16 + lm) << 6) + sw);
            #pragma unroll
            for (int i = 0; i < 4; i++)
                #pragma unroll
                for (int j = 0; j < 2; j++)
                    acc[i][j] = __builtin_amdgcn_mfma_f32_16x16x32_bf16(b[j], a[i], acc[i][j], 0, 0, 0);
        }
    }
    #pragma unroll
    for (int j = 0; j < 2; j++) {
        int nb = n0 + wn * 32 + j * 16 + qm * 4;
        float4 b4 = *(const float4*)(bo + nb);
        #pragma unroll
        for (int i = 0; i < 4; i++) {
            int m = m0 + wm * 64 + i * 16 + lm;
            float4 st;
            st.x = acc[i][j][0] + b4.x;
            st.y = acc[i][j][1] + b4.y;
            st.z = acc[i][j][2] + b4.z;
            st.w = acc[i][j][3] + b4.w;
            *(float4*)(Out + (size_t)m * DD + nb) = st;
        }
    }
}

extern "C" void kernel_launch(void* const* d_in, const int* in_sizes, int n_in,
                              void* d_out, int out_size, void* d_ws, size_t ws_size,
                              hipStream_t stream) {
    const float* x   = (const float*)d_in[0];
    const float* Wq  = (const float*)d_in[1];
    const float* bq  = (const float*)d_in[2];
    const float* Wk  = (const float*)d_in[3];
    const float* bk  = (const float*)d_in[4];
    const float* Wv_ = (const float*)d_in[5];
    const float* bv  = (const float*)d_in[6];
    const float* Wo  = (const float*)d_in[7];
    const float* bo  = (const float*)d_in[8];
    float* out = (float*)d_out;

    ushort* xb  = (ushort*)d_ws;
    ushort* W3T = xb  + (size_t)BB * SS * DD;
    ushort* Wob = W3T + (size_t)3 * HH * HD * DD;
    ushort* qb  = Wob + (size_t)DD * DD;
    ushort* kb  = qb + (size_t)BB * SS * DD;
    ushort* vT  = kb + (size_t)BB * SS * DD;
    ushort* wvb = vT + (size_t)BB * SS * DD;

    prep<<<dim3(5888), 256, 0, stream>>>(x, Wo, Wq, Wk, Wv_, xb, Wob, W3T);
    gemm_qkv<<<dim3(32, 16), 256, 0, stream>>>(xb, W3T, bq, bk, bv, qb, kb, vT);
    attn<<<dim3(1024), 256, 0, stream>>>(qb, kb, vT, wvb);
    gemm_out<<<dim3(32, 16), 256, 0, stream>>>(wvb, Wob, bo, out);
}

// Round 6
// 170.702 us; speedup vs baseline: 1.0995x; 1.0260x over previous
//
#include <hip/hip_runtime.h>

// Attention_77730318123148 — B=2,S=2048,D=1024,H=16,HD=64. fp32 I/O, bf16 MFMA compute.
// R17 = R16 with permlane32_swap FIXED. HW semantics (derived from guide's verified
// m214v22 recipe): swap(d,s) exchanges d's HIGH 32 lanes with s's LOW 32 lanes.
// Call order now pl32_swap(c01,c45)/(c23,c67); fallback rewritten to same semantics.
// attn: 32x32x16 MFMA + in-register P; 16 ds_read_b128 / 0 ds_write per wave-tile.
// 4-wave blocks, jt-parity pair split, quarter-balanced 1024 grid, 40KB LDS -> 4 blk/CU.
// gemm_qkv / gemm_out / prep unchanged.

#define DD 1024
#define SS 2048
#define BB 2
#define HH 16
#define HD 64
#define QSCALE 0.18033688011112042f   // 0.125 * log2(e)

typedef __attribute__((ext_vector_type(8))) short short8;   // 8 bf16 (A/B frag)
typedef __attribute__((ext_vector_type(4))) float float4v;  // C/D frag (16x16)
typedef __attribute__((ext_vector_type(16))) float f32x16;  // C/D frag (32x32)
typedef __attribute__((ext_vector_type(4))) uint uint4v;
typedef unsigned short ushort;
typedef unsigned int uint;

__device__ inline ushort f2bf(float f) {       // RNE (input conversion fidelity)
    union { float f; uint i; } v; v.f = f;
    uint r = v.i + 0x7FFF + ((v.i >> 16) & 1);
    return (ushort)(r >> 16);
}
#if __has_builtin(__builtin_amdgcn_cvt_pk_bf16_f32)
typedef __bf16 bf16x2 __attribute__((ext_vector_type(2)));
__device__ inline uint pack_bf2(float a, float b) {   // 1 inst, RNE
    union { bf16x2 v; uint u; } c;
    c.v = __builtin_amdgcn_cvt_pk_bf16_f32(a, b);
    return c.u;
}
#else
__device__ inline uint pack_bf2(float a, float b) {   // fallback: round-half-up
    union { float f; uint i; } x, y; x.f = a; y.f = b;
    return ((x.i + 0x8000u) >> 16) | (((y.i + 0x8000u) >> 16) << 16);
}
#endif

__device__ inline short8 u4_to_s8(uint4v u) {
    union { uint4v u; short8 s; } cv; cv.u = u; return cv.s;
}

// permlane32_swap semantics (gfx950 HW): d.lanes[32:63] <-> s.lanes[0:31].
// After swap: d' = {lo: d.lo, hi: s.lo}; s' = {lo: d.hi, hi: s.hi}.
#if __has_builtin(__builtin_amdgcn_permlane32_swap)
typedef unsigned uint2v __attribute__((ext_vector_type(2)));
__device__ inline void pl32_swap(uint& d, uint& s) {
    uint2v r = __builtin_amdgcn_permlane32_swap(d, s, false, false);
    d = r[0]; s = r[1];
}
#else
__device__ inline void pl32_swap(uint& d, uint& s) {
    uint dx = __shfl_xor(d, 32, 64), sx = __shfl_xor(s, 32, 64);
    bool hi = (threadIdx.x & 32) != 0;
    uint nd = hi ? sx : d;   // d'[hi] = s[lo] (sx in hi lanes); d'[lo] = d[lo]
    uint ns = hi ? s : dx;   // s'[lo] = d[hi] (dx in lo lanes); s'[hi] = s[hi]
    d = nd; s = ns;
}
#endif

__device__ __forceinline__ void cp16(const ushort* g, ushort* l) {
    __builtin_amdgcn_global_load_lds((const __attribute__((address_space(1))) void*)g,
                                     (__attribute__((address_space(3))) void*)l,
                                     16, 0, 0);
}

// ---------------- prep: cvt x (4096 blk) | cvt Wo (1024 blk) | transpose W3 (768 blk) ----
__global__ __launch_bounds__(256) void prep(const float* __restrict__ x,
                                            const float* __restrict__ Wo,
                                            const float* __restrict__ Wq,
                                            const float* __restrict__ Wk,
                                            const float* __restrict__ Wv,
                                            ushort* __restrict__ xb,
                                            ushort* __restrict__ Wob,
                                            ushort* __restrict__ W3T) {
    __shared__ ushort T[64][65];
    int bid = blockIdx.x, t = threadIdx.x;
    if (bid < 5120) {
        const float* src; ushort* dst; int j;
        if (bid < 4096) { src = x;  dst = xb;  j = bid * 256 + t; }
        else            { src = Wo; dst = Wob; j = (bid - 4096) * 256 + t; }
        float4 v = ((const float4*)src)[j];
        ushort o[4] = { f2bf(v.x), f2bf(v.y), f2bf(v.z), f2bf(v.w) };
        ((uint2*)dst)[j] = *(const uint2*)o;
        return;
    }
    int i = bid - 5120;
    int z = i >> 8, h = (i >> 4) & 15, d0 = (i & 15) * 64;
    const float* W = z == 0 ? Wq : (z == 1 ? Wk : Wv);
    const float* Wh = W + h * DD * HD;
    ushort* Wt = W3T + ((size_t)z * HH + h) * HD * DD;
    #pragma unroll
    for (int s = 0; s < 4; s++) {
        int idx = t + s * 256;
        int d = idx >> 4, e4 = (idx & 15) * 4;
        float4 v = *(const float4*)(Wh + (d0 + d) * HD + e4);
        T[d][e4 + 0] = f2bf(v.x); T[d][e4 + 1] = f2bf(v.y);
        T[d][e4 + 2] = f2bf(v.z); T[d][e4 + 3] = f2bf(v.w);
    }
    __syncthreads();
    #pragma unroll
    for (int s = 0; s < 2; s++) {
        int idx = t + s * 256;
        int e = idx >> 3, d8 = (idx & 7) * 8;
        ushort tmp[8];
        #pragma unroll
        for (int j = 0; j < 8; j++) tmp[j] = T[d8 + j][e];
        *(uint4*)(Wt + e * DD + d0 + d8) = *(uint4*)tmp;
    }
}

// ---- QKV fused: xb[4096,1024] x {Wq,Wk,Wv}T (NT). M-tile 128, N-tile 64, BK=64.
__global__ __launch_bounds__(256) void gemm_qkv(const ushort* __restrict__ xb,
                                                const ushort* __restrict__ W3T,
                                                const float* __restrict__ bq,
                                                const float* __restrict__ bk,
                                                const float* __restrict__ bv,
                                                ushort* __restrict__ qb,
                                                ushort* __restrict__ kb,
                                                ushort* __restrict__ vT) {
    __shared__ ushort Al[128 * 64];      // 16 KB, XOR-swizzled chunks
    __shared__ ushort Bl[3][64 * 64];    // 3 x 8 KB, XOR-swizzled
    int m0 = blockIdx.x * 128, n0 = blockIdx.y * 64;
    int t = threadIdx.x, lane = t & 63, w = t >> 6;
    int wm = w & 1, wn = w >> 1;
    int qm = lane >> 4, lm = lane & 15;

    const ushort* W0 = W3T + (size_t)n0 * DD;
    const ushort* W1 = W3T + (size_t)(HH * HD + n0) * DD;
    const ushort* W2 = W3T + (size_t)(2 * HH * HD + n0) * DD;

    float4v acc[3][4][2] = {};
    for (int k0 = 0; k0 < DD; k0 += 64) {
        __syncthreads();
        #pragma unroll
        for (int s = 0; s < 4; s++) {
            int c = t + s * 256;
            int row = c >> 3;
            int j = (c & 7) ^ (row & 7);
            cp16(xb + (size_t)(m0 + row) * DD + k0 + j * 8, Al + c * 8);
        }
        #pragma unroll
        for (int s = 0; s < 2; s++) {
            int c = t + s * 256;
            int row = c >> 3;
            int j = (c & 7) ^ (row & 7);
            cp16(W0 + (size_t)row * DD + k0 + j * 8, Bl[0] + c * 8);
            cp16(W1 + (size_t)row * DD + k0 + j * 8, Bl[1] + c * 8);
            cp16(W2 + (size_t)row * DD + k0 + j * 8, Bl[2] + c * 8);
        }
        __syncthreads();
        #pragma unroll
        for (int h2 = 0; h2 < 2; h2++) {
            int sw = ((((h2 << 2) | qm) ^ (lm & 7)) << 3);
            short8 a[4];
            #pragma unroll
            for (int i = 0; i < 4; i++)
                a[i] = *(const short8*)(Al + ((wm * 64 + i * 16 + lm) << 6) + sw);
            #pragma unroll
            for (int z = 0; z < 3; z++) {
                short8 b0 = *(const short8*)(Bl[z] + ((wn * 32 + lm) << 6) + sw);
                short8 b1 = *(const short8*)(Bl[z] + ((wn * 32 + 16 + lm) << 6) + sw);
                if (z == 2) {
                    #pragma unroll
                    for (int i = 0; i < 4; i++) {
                        acc[2][i][0] = __builtin_amdgcn_mfma_f32_16x16x32_bf16(a[i], b0, acc[2][i][0], 0, 0, 0);
                        acc[2][i][1] = __builtin_amdgcn_mfma_f32_16x16x32_bf16(a[i], b1, acc[2][i][1], 0, 0, 0);
                    }
                } else {   // swapped: D rows = n (4 consec per lane), cols = m
                    #pragma unroll
                    for (int i = 0; i < 4; i++) {
                        acc[z][i][0] = __builtin_amdgcn_mfma_f32_16x16x32_bf16(b0, a[i], acc[z][i][0], 0, 0, 0);
                        acc[z][i][1] = __builtin_amdgcn_mfma_f32_16x16x32_bf16(b1, a[i], acc[z][i][1], 0, 0, 0);
                    }
                }
            }
        }
    }
    #pragma unroll
    for (int z = 0; z < 2; z++) {
        const float* bias = z == 0 ? bq : bk;
        ushort* Out = z == 0 ? qb : kb;
        float sc = z == 0 ? QSCALE : 1.0f;
        #pragma unroll
        for (int j = 0; j < 2; j++) {
            int nb = n0 + wn * 32 + j * 16 + qm * 4;
            float4 b4 = *(const float4*)(bias + nb);
            #pragma unroll
            for (int i = 0; i < 4; i++) {
                int m = m0 + wm * 64 + i * 16 + lm;
                uint2 o2;
                o2.x = pack_bf2((acc[z][i][j][0] + b4.x) * sc, (acc[z][i][j][1] + b4.y) * sc);
                o2.y = pack_bf2((acc[z][i][j][2] + b4.z) * sc, (acc[z][i][j][3] + b4.w) * sc);
                *(uint2*)(Out + (size_t)m * DD + nb) = o2;
            }
        }
    }
    #pragma unroll
    for (int j = 0; j < 2; j++) {
        int n = n0 + wn * 32 + j * 16 + lm;
        int h = n >> 6, e = n & 63;
        float bb = bv[n];
        #pragma unroll
        for (int i = 0; i < 4; i++) {
            int m = m0 + wm * 64 + i * 16 + qm * 4;
            int b_ = m >> 11, s = m & (SS - 1);
            uint2 o2;
            o2.x = pack_bf2(acc[2][i][j][0] + bb, acc[2][i][j][1] + bb);
            o2.y = pack_bf2(acc[2][i][j][2] + bb, acc[2][i][j][3] + bb);
            *(uint2*)(vT + ((size_t)(b_ * HH + h) * HD + e) * SS + s) = o2;
        }
    }
}

// -------- flash attention (causal), S^T form, static-max softmax, 32x32x16 MFMA,
// -------- in-register P via cvt_pk + permlane32_swap. jt-parity pair split.
// -------- LDS (ushort offs): Ql 0, KA 4096, VA 8192, KB 12288, VB 16384 (8KB tiles).
// -------- Total 40KB -> 4 blocks/CU. Grid 1024 quarter-balanced qt map (66 units/CU).
__global__ __launch_bounds__(256, 4) void attn(const ushort* __restrict__ Q,
                                               const ushort* __restrict__ K,
                                               const ushort* __restrict__ VT,
                                               ushort* __restrict__ O) {
    __shared__ ushort LB[20480];          // 40 KB
    int id = blockIdx.x;
    int bh = id & 31;
    int j5 = (id >> 5) & 7;
    int quad = id >> 8;
    int qt = (quad == 0) ? (31 - j5) : (quad == 1) ? (16 + j5)
           : (quad == 2) ? (15 - j5) : j5;
    int b = bh >> 4, h = bh & 15;
    int m0 = qt * 64;
    const ushort* Qp = Q + (size_t)b * SS * DD + h * HD;
    const ushort* Kp = K + (size_t)b * SS * DD + h * HD;
    const ushort* Vp = VT + (size_t)bh * HD * SS;
    int t = threadIdx.x, lane = t & 63, w = t >> 6;      // w in [0,4)
    int pr = w >> 1, wq = w & 1;                         // pair (jt parity), q-half
    int ln = lane & 31, hi = lane >> 5;
    int c0 = t, c1 = t + 256;
    int r0 = c0 >> 3, s0 = (c0 & 7) ^ (r0 & 7);
    int r1 = c1 >> 3, s1 = (c1 & 7) ^ (r1 & 7);

    // stage Q + tile0 -> A bufs (+ tile1 -> B bufs if present); XOR-swizzled source
    cp16(Qp + (size_t)(m0 + r0) * DD + s0 * 8, LB + c0 * 8);
    cp16(Qp + (size_t)(m0 + r1) * DD + s1 * 8, LB + c1 * 8);
    cp16(Kp + (size_t)r0 * DD + s0 * 8, LB + 4096 + c0 * 8);
    cp16(Kp + (size_t)r1 * DD + s1 * 8, LB + 4096 + c1 * 8);
    cp16(Vp + (size_t)r0 * SS + s0 * 8, LB + 8192 + c0 * 8);
    cp16(Vp + (size_t)r1 * SS + s1 * 8, LB + 8192 + c1 * 8);
    if (qt >= 1) {
        cp16(Kp + (size_t)(64 + r0) * DD + s0 * 8, LB + 12288 + c0 * 8);
        cp16(Kp + (size_t)(64 + r1) * DD + s1 * 8, LB + 12288 + c1 * 8);
        cp16(Vp + (size_t)r0 * SS + 64 + s0 * 8, LB + 16384 + c0 * 8);
        cp16(Vp + (size_t)r1 * SS + 64 + s1 * 8, LB + 16384 + c1 * 8);
    }
    __syncthreads();

    // hoist Q B-frags: lane holds n=q=(wq*32+ln), d = ds*16 + hi*8 + j  (Q prescaled)
    short8 qf[4];
    int qrow = wq * 32 + ln;
    #pragma unroll
    for (int ds_ = 0; ds_ < 4; ds_++)
        qf[ds_] = *(const short8*)(LB + (qrow << 6) + ((((ds_ << 1) | hi) ^ (qrow & 7)) << 3));

    ushort* Kb = LB + 4096 + pr * 8192;    // KA or KB
    ushort* Vb = LB + 8192 + pr * 8192;    // VA or VB
    f32x16 o[2] = {};                      // [etile]; D rows=e, cols=q
    float li = 0.f;
    int nss = (qt + 2) >> 1;

    for (int ss = 0; ss < nss; ss++) {
        int myjt = 2 * ss + pr;
        if (myjt <= qt) {
            #pragma unroll
            for (int kt = 0; kt < 2; kt++) {
                // St = K·Q^T (32x32): lane holds col q, rows k = kt*32+(r&3)+8*(r>>2)+4*hi
                f32x16 sacc = {};
                __builtin_amdgcn_s_setprio(1);
                #pragma unroll
                for (int ds_ = 0; ds_ < 4; ds_++) {
                    int row = kt * 32 + ln;
                    short8 ak = *(const short8*)(Kb + (row << 6) + ((((ds_ << 1) | hi) ^ (row & 7)) << 3));
                    sacc = __builtin_amdgcn_mfma_f32_32x32x16_bf16(ak, qf[ds_], sacc, 0, 0, 0);
                }
                __builtin_amdgcn_s_setprio(0);
                if (myjt == qt) {   // diagonal tile: mask k > q (tile-local compare)
                    #pragma unroll
                    for (int r = 0; r < 16; r++) {
                        int kk = kt * 32 + (r & 3) + 8 * (r >> 2) + 4 * hi;
                        if (kk > qrow) sacc[r] = -__builtin_inff();
                    }
                }
                // p = exp2(s); li; pack to PV B-frags in-register (T12)
                float p[16];
                #pragma unroll
                for (int r = 0; r < 16; r++) {
                    p[r] = __builtin_amdgcn_exp2f(sacc[r]);
                    li += p[r];
                }
                uint4v pw[2];
                #pragma unroll
                for (int ks = 0; ks < 2; ks++) {
                    uint c01 = pack_bf2(p[ks * 8 + 0], p[ks * 8 + 1]);
                    uint c23 = pack_bf2(p[ks * 8 + 2], p[ks * 8 + 3]);
                    uint c45 = pack_bf2(p[ks * 8 + 4], p[ks * 8 + 5]);
                    uint c67 = pack_bf2(p[ks * 8 + 6], p[ks * 8 + 7]);
                    // HW semantics: d.hi <-> s.lo. After these, c01/c23 = words 0/1,
                    // c45/c67 = words 2/3 of the B-frag (verified vs m214 recipe).
                    pl32_swap(c01, c45);
                    pl32_swap(c23, c67);
                    uint4v pv; pv[0] = c01; pv[1] = c23; pv[2] = c45; pv[3] = c67;
                    pw[ks] = pv;
                }
                // O += V^T·P (32x32): A = V rows e, k-axis = attn k; B = P frags
                __builtin_amdgcn_s_setprio(1);
                #pragma unroll
                for (int et = 0; et < 2; et++) {
                    #pragma unroll
                    for (int ks = 0; ks < 2; ks++) {
                        int row = et * 32 + ln;
                        int ch = ((kt << 2) | (ks << 1) | hi) ^ (row & 7);
                        short8 av = *(const short8*)(Vb + (row << 6) + (ch << 3));
                        o[et] = __builtin_amdgcn_mfma_f32_32x32x16_bf16(av, u4_to_s8(pw[ks]), o[et], 0, 0, 0);
                    }
                }
                __builtin_amdgcn_s_setprio(0);
            }
        }
        __syncthreads();               // both pairs done reading their buffers
        int nx = 2 * ss + 2;
        if (nx <= qt) {                // stage next even tile -> A bufs
            cp16(Kp + (size_t)(nx * 64 + r0) * DD + s0 * 8, LB + 4096 + c0 * 8);
            cp16(Kp + (size_t)(nx * 64 + r1) * DD + s1 * 8, LB + 4096 + c1 * 8);
            cp16(Vp + (size_t)r0 * SS + nx * 64 + s0 * 8, LB + 8192 + c0 * 8);
            cp16(Vp + (size_t)r1 * SS + nx * 64 + s1 * 8, LB + 8192 + c1 * 8);
        }
        if (nx + 1 <= qt) {            // stage next odd tile -> B bufs
            cp16(Kp + (size_t)((nx + 1) * 64 + r0) * DD + s0 * 8, LB + 12288 + c0 * 8);
            cp16(Kp + (size_t)((nx + 1) * 64 + r1) * DD + s1 * 8, LB + 12288 + c1 * 8);
            cp16(Vp + (size_t)r0 * SS + (nx + 1) * 64 + s0 * 8, LB + 16384 + c0 * 8);
            cp16(Vp + (size_t)r1 * SS + (nx + 1) * 64 + s1 * 8, LB + 16384 + c1 * 8);
        }
        __syncthreads();               // staged tiles ready (vmcnt drained here)
    }

    // combine pair partials: O = O_A + O_B, li = li_A + li_B (static-max softmax)
    float* cb = (float*)(LB + 4096);       // [2][64][32] floats = 16 KB (over KA+VA)
    float* cl = (float*)(LB + 12288);      // [2][64] floats (over KB start)
    if (pr == 1) {
        float* dst = cb + ((size_t)(wq * 64 + lane)) * 32;
        #pragma unroll
        for (int et = 0; et < 2; et++)
            #pragma unroll
            for (int g2 = 0; g2 < 4; g2++) {
                int slot = et * 4 + g2;
                float4v v4;
                v4[0] = o[et][g2 * 4 + 0]; v4[1] = o[et][g2 * 4 + 1];
                v4[2] = o[et][g2 * 4 + 2]; v4[3] = o[et][g2 * 4 + 3];
                *(float4v*)(dst + ((slot ^ (lane & 7)) << 2)) = v4;
            }
        cl[wq * 64 + lane] = li;
    }
    __syncthreads();
    if (pr == 0) {
        float* src = cb + ((size_t)(wq * 64 + lane)) * 32;
        #pragma unroll
        for (int et = 0; et < 2; et++)
            #pragma unroll
            for (int g2 = 0; g2 < 4; g2++) {
                int slot = et * 4 + g2;
                float4v v4 = *(const float4v*)(src + ((slot ^ (lane & 7)) << 2));
                o[et][g2 * 4 + 0] += v4[0]; o[et][g2 * 4 + 1] += v4[1];
                o[et][g2 * 4 + 2] += v4[2]; o[et][g2 * 4 + 3] += v4[3];
            }
        li += cl[wq * 64 + lane];
        li += __shfl_xor(li, 32, 64);      // lanes l, l+32 share q = ln
        float inv = 1.f / li;
        int qg = m0 + wq * 32 + ln;
        ushort* Ob = O + ((size_t)b * SS + qg) * DD + h * HD;
        #pragma unroll
        for (int et = 0; et < 2; et++)
            #pragma unroll
            for (int g2 = 0; g2 < 4; g2++) {
                int ec = et * 32 + g2 * 8 + hi * 4;   // e = (r&3)+8*(r>>2)+4*hi
                uint2 u;
                u.x = pack_bf2(o[et][g2 * 4 + 0] * inv, o[et][g2 * 4 + 1] * inv);
                u.y = pack_bf2(o[et][g2 * 4 + 2] * inv, o[et][g2 * 4 + 3] * inv);
                *(uint2*)(Ob + ec) = u;
            }
    }
}

// ---- out proj: wvb[4096,1024] x Wob^T (NT, 128x64, BK=64, swizzled; 16B fp32 stores) ----
__global__ __launch_bounds__(256) void gemm_out(const ushort* __restrict__ X,
                                                const ushort* __restrict__ Wob,
                                                const float* __restrict__ bo,
                                                float* __restrict__ Out) {
    __shared__ ushort Al[128 * 64];
    __shared__ ushort Bl[64 * 64];
    int m0 = blockIdx.x * 128, n0 = blockIdx.y * 64;
    int t = threadIdx.x, lane = t & 63, w = t >> 6;
    int wm = w & 1, wn = w >> 1;
    int qm = lane >> 4, lm = lane & 15;

    float4v acc[4][2] = {};
    for (int k0 = 0; k0 < DD; k0 += 64) {
        __syncthreads();
        #pragma unroll
        for (int s = 0; s < 4; s++) {
            int c = t + s * 256;
            int row = c >> 3;
            int j = (c & 7) ^ (row & 7);
            cp16(X + (size_t)(m0 + row) * DD + k0 + j * 8, Al + c * 8);
        }
        #pragma unroll
        for (int s = 0; s < 2; s++) {
            int c = t + s * 256;
            int row = c >> 3;
            int j = (c & 7) ^ (row & 7);
            cp16(Wob + (size_t)(n0 + row) * DD + k0 + j * 8, Bl + c * 8);
        }
        __syncthreads();
        #pragma unroll
        for (int h2 = 0; h2 < 2; h2++) {
            int sw = ((((h2 << 2) | qm) ^ (lm & 7)) << 3);
            short8 a[4], b[2];
            #pragma unroll
            for (int i = 0; i < 4; i++)
                a[i] = *(const short8*)(Al + ((wm * 64 + i * 16 + lm) << 6) + sw);
            #pragma unroll
            for (int j = 0; j < 2; j++)
                b[j] = *(const short8*)(Bl + ((wn * 32 + j * 16 + lm) << 6) + sw);
            #pragma unroll
            for (int i = 0; i < 4; i++)
                #pragma unroll
                for (int j = 0; j < 2; j++)
                    acc[i][j] = __builtin_amdgcn_mfma_f32_16x16x32_bf16(b[j], a[i], acc[i][j], 0, 0, 0);
        }
    }
    #pragma unroll
    for (int j = 0; j < 2; j++) {
        int nb = n0 + wn * 32 + j * 16 + qm * 4;
        float4 b4 = *(const float4*)(bo + nb);
        #pragma unroll
        for (int i = 0; i < 4; i++) {
            int m = m0 + wm * 64 + i * 16 + lm;
            float4 st;
            st.x = acc[i][j][0] + b4.x;
            st.y = acc[i][j][1] + b4.y;
            st.z = acc[i][j][2] + b4.z;
            st.w = acc[i][j][3] + b4.w;
            *(float4*)(Out + (size_t)m * DD + nb) = st;
        }
    }
}

extern "C" void kernel_launch(void* const* d_in, const int* in_sizes, int n_in,
                              void* d_out, int out_size, void* d_ws, size_t ws_size,
                              hipStream_t stream) {
    const float* x   = (const float*)d_in[0];
    const float* Wq  = (const float*)d_in[1];
    const float* bq  = (const float*)d_in[2];
    const float* Wk  = (const float*)d_in[3];
    const float* bk  = (const float*)d_in[4];
    const float* Wv_ = (const float*)d_in[5];
    const float* bv  = (const float*)d_in[6];
    const float* Wo  = (const float*)d_in[7];
    const float* bo  = (const float*)d_in[8];
    float* out = (float*)d_out;

    ushort* xb  = (ushort*)d_ws;
    ushort* W3T = xb  + (size_t)BB * SS * DD;
    ushort* Wob = W3T + (size_t)3 * HH * HD * DD;
    ushort* qb  = Wob + (size_t)DD * DD;
    ushort* kb  = qb + (size_t)BB * SS * DD;
    ushort* vT  = kb + (size_t)BB * SS * DD;
    ushort* wvb = vT + (size_t)BB * SS * DD;

    prep<<<dim3(5888), 256, 0, stream>>>(x, Wo, Wq, Wk, Wv_, xb, Wob, W3T);
    gemm_qkv<<<dim3(32, 16), 256, 0, stream>>>(xb, W3T, bq, bk, bv, qb, kb, vT);
    attn<<<dim3(1024), 256, 0, stream>>>(qb, kb, vT, wvb);
    gemm_out<<<dim3(32, 16), 256, 0, stream>>>(wvb, Wob, bo, out);
}